// Round 1
// baseline (553.446 us; speedup 1.0000x reference)
//
#include <hip/hip_runtime.h>
#include <math.h>

// Problem constants (from reference): N=8192, F=256, HID=128, C=64
#define NROWS 8192
#define EDGE_CAP 256   // max edges/row; Binomial(8192,0.005) max ~70, 256 is very safe

// ---------------------------------------------------------------------------
// K1: dense adjacency -> fixed-stride CSR (wave per row, ballot compaction)
// ---------------------------------------------------------------------------
__global__ __launch_bounds__(256) void build_csr(const float* __restrict__ adj,
                                                 int* __restrict__ cnt,
                                                 int* __restrict__ col) {
    int row  = blockIdx.x * 4 + (threadIdx.x >> 6);
    int lane = threadIdx.x & 63;
    const float4* arow = (const float4*)(adj + (size_t)row * NROWS);
    int* crow = col + (size_t)row * EDGE_CAP;
    int count = 0;
    for (int it = 0; it < NROWS / 256; ++it) {   // 32 iters: 64 lanes x float4
        float4 v = arow[it * 64 + lane];
        float vv[4] = {v.x, v.y, v.z, v.w};
        #pragma unroll
        for (int p = 0; p < 4; ++p) {
            bool nz = vv[p] > 0.0f;
            unsigned long long m = __ballot(nz);
            if (nz) {
                int off = count + __popcll(m & ((1ull << lane) - 1ull));
                if (off < EDGE_CAP) crow[off] = it * 256 + lane * 4 + p;
            }
            count += __popcll(m);   // wave-uniform
        }
    }
    if (lane == 0) cnt[row] = count < EDGE_CAP ? count : EDGE_CAP;
}

// ---------------------------------------------------------------------------
// K2: S[i,:] = sum_{j in N(i)} X[j,:]   (adj values are exactly 1.0)
// block per row, thread per column
// ---------------------------------------------------------------------------
template <int FD>
__global__ void spmm_sum(const int* __restrict__ cnt, const int* __restrict__ col,
                         const float* __restrict__ X, float* __restrict__ S) {
    int row = blockIdx.x;
    int c   = threadIdx.x;            // blockDim.x == FD
    int n   = cnt[row];
    const int* cr = col + (size_t)row * EDGE_CAP;
    float acc = 0.0f;
    for (int e = 0; e < n; ++e) {
        int j = cr[e];
        acc += X[(size_t)j * FD + c];
    }
    S[(size_t)row * FD + c] = acc;
}

// ---------------------------------------------------------------------------
// K3: H = S @ W[:KD] + X @ W[KD:]   (concat GEMM, split algebraically)
// 64x64 tile, 256 threads, 4x4 per thread, fp32
// ---------------------------------------------------------------------------
template <int KD, int ND>
__global__ __launch_bounds__(256) void gemm_concat(const float* __restrict__ A0,
                                                   const float* __restrict__ A1,
                                                   const float* __restrict__ W,
                                                   float* __restrict__ H) {
    const int BM = 64, BN = 64, BK = 16;
    __shared__ float As[BK][BM];
    __shared__ float Bs[BK][BN];
    int bm = blockIdx.x, bn = blockIdx.y;
    int tid = threadIdx.x;
    int tx = tid & 15, ty = tid >> 4;
    float acc[4][4] = {};
    for (int half = 0; half < 2; ++half) {
        const float* A  = half ? A1 : A0;
        const float* Wh = W + (size_t)half * KD * ND;
        for (int k0 = 0; k0 < KD; k0 += BK) {
            {   // A tile: 64 rows x 16 k  (4 threads per row, float4 each)
                int r  = tid >> 2;
                int kk = (tid & 3) * 4;
                float4 v = *(const float4*)&A[(size_t)(bm * 64 + r) * KD + k0 + kk];
                As[kk + 0][r] = v.x; As[kk + 1][r] = v.y;
                As[kk + 2][r] = v.z; As[kk + 3][r] = v.w;
            }
            {   // B tile: 16 k x 64 n
                int kk = tid >> 4;
                int n4 = (tid & 15) * 4;
                *(float4*)&Bs[kk][n4] =
                    *(const float4*)&Wh[(size_t)(k0 + kk) * ND + bn * 64 + n4];
            }
            __syncthreads();
            #pragma unroll
            for (int kk = 0; kk < BK; ++kk) {
                float a[4], b[4];
                #pragma unroll
                for (int i = 0; i < 4; ++i) a[i] = As[kk][ty * 4 + i];
                #pragma unroll
                for (int i = 0; i < 4; ++i) b[i] = Bs[kk][tx * 4 + i];
                #pragma unroll
                for (int i = 0; i < 4; ++i)
                    #pragma unroll
                    for (int j = 0; j < 4; ++j) acc[i][j] += a[i] * b[j];
            }
            __syncthreads();
        }
    }
    #pragma unroll
    for (int i = 0; i < 4; ++i) {
        int r = bm * 64 + ty * 4 + i;
        float4 v = {acc[i][0], acc[i][1], acc[i][2], acc[i][3]};
        *(float4*)&H[(size_t)r * ND + bn * 64 + tx * 4] = v;
    }
}

// ---------------------------------------------------------------------------
// K4: src[i] = H[i,:] . a[:FOUT],  dst[i] = H[i,:] . a[FOUT:]
// wave per row
// ---------------------------------------------------------------------------
template <int FOUT>
__global__ __launch_bounds__(256) void attn_scores(const float* __restrict__ H,
                                                   const float* __restrict__ a,
                                                   float* __restrict__ src,
                                                   float* __restrict__ dst) {
    int row  = blockIdx.x * 4 + (threadIdx.x >> 6);
    int lane = threadIdx.x & 63;
    const float* h = H + (size_t)row * FOUT;
    float s1 = 0.0f, s2 = 0.0f;
    #pragma unroll
    for (int k = lane; k < FOUT; k += 64) {
        float hv = h[k];
        s1 += hv * a[k];
        s2 += hv * a[FOUT + k];
    }
    #pragma unroll
    for (int off = 32; off; off >>= 1) {
        s1 += __shfl_down(s1, off);
        s2 += __shfl_down(s2, off);
    }
    if (lane == 0) { src[row] = s1; dst[row] = s2; }
}

// ---------------------------------------------------------------------------
// K5: per-row masked softmax over edges + hp = att @ H, fused epilogue
// MODE 0: ELU (layer 1 output)    MODE 1: log_softmax over 64 classes
// wave per row (4 rows per 256-thread block)
// ---------------------------------------------------------------------------
template <int FOUT, int MODE>
__global__ __launch_bounds__(256) void attn_aggregate(const int* __restrict__ cnt,
                                                      const int* __restrict__ col,
                                                      const float* __restrict__ H,
                                                      const float* __restrict__ src,
                                                      const float* __restrict__ dst,
                                                      float* __restrict__ out) {
    __shared__ float pbuf[4][EDGE_CAP];
    __shared__ int   cbuf[4][EDGE_CAP];
    int wav  = threadIdx.x >> 6;
    int lane = threadIdx.x & 63;
    int row  = blockIdx.x * 4 + wav;
    int n    = cnt[row];
    const int* cr = col + (size_t)row * EDGE_CAP;
    float si = src[row];

    // pass 1: e = leaky_relu(src_i + dst_j), row max
    float m = -3.0e38f;
    for (int e = lane; e < n; e += 64) {
        int j = cr[e];
        float x = si + dst[j];
        x = x > 0.0f ? x : 0.2f * x;
        cbuf[wav][e] = j;
        pbuf[wav][e] = x;
        m = fmaxf(m, x);
    }
    #pragma unroll
    for (int off = 32; off; off >>= 1) m = fmaxf(m, __shfl_xor(m, off));

    // pass 2: exp, row sum  (non-edges contribute exp(-9e15 - m) == 0 exactly)
    float ssum = 0.0f;
    for (int e = lane; e < n; e += 64) {
        float p = __expf(pbuf[wav][e] - m);
        pbuf[wav][e] = p;
        ssum += p;
    }
    #pragma unroll
    for (int off = 32; off; off >>= 1) ssum += __shfl_xor(ssum, off);
    float inv = 1.0f / ssum;

    __syncthreads();   // cross-lane LDS visibility for the broadcast reads below

    // pass 3: hp[i,c] = (1/sum) * sum_e p_e * H[j_e, c]; lanes = columns
    constexpr int NC = FOUT / 64;
    float acc[NC];
    #pragma unroll
    for (int i = 0; i < NC; ++i) acc[i] = 0.0f;
    for (int e = 0; e < n; ++e) {
        int j   = cbuf[wav][e];
        float p = pbuf[wav][e];
        #pragma unroll
        for (int i = 0; i < NC; ++i)
            acc[i] += p * H[(size_t)j * FOUT + i * 64 + lane];
    }

    if (MODE == 0) {
        #pragma unroll
        for (int i = 0; i < NC; ++i) {
            float v = acc[i] * inv;
            v = v > 0.0f ? v : (__expf(v) - 1.0f);   // ELU, alpha=1
            out[(size_t)row * FOUT + i * 64 + lane] = v;
        }
    } else {
        // FOUT == 64: one class per lane; fused log_softmax across the wave
        float logit = acc[0] * inv;
        float mm = logit;
        #pragma unroll
        for (int off = 32; off; off >>= 1) mm = fmaxf(mm, __shfl_xor(mm, off));
        float se = __expf(logit - mm);
        #pragma unroll
        for (int off = 32; off; off >>= 1) se += __shfl_xor(se, off);
        out[(size_t)row * 64 + lane] = logit - mm - logf(se);
    }
}

// ---------------------------------------------------------------------------
extern "C" void kernel_launch(void* const* d_in, const int* in_sizes, int n_in,
                              void* d_out, int out_size, void* d_ws, size_t ws_size,
                              hipStream_t stream) {
    const float* feat = (const float*)d_in[0];   // (8192, 256)
    const float* adj  = (const float*)d_in[1];   // (8192, 8192)
    const float* W0   = (const float*)d_in[2];   // (512, 128)
    const float* a0   = (const float*)d_in[3];   // (256,)
    const float* W1   = (const float*)d_in[4];   // (256, 64)
    const float* a1   = (const float*)d_in[5];   // (128,)
    float* out = (float*)d_out;                  // (8192, 64)

    // workspace layout (~30.3 MB total)
    char* w = (char*)d_ws;
    int* cnt = (int*)w;                w += (size_t)NROWS * sizeof(int);
    int* col = (int*)w;                w += (size_t)NROWS * EDGE_CAP * sizeof(int);
    float* S1   = (float*)w;           w += (size_t)NROWS * 256 * sizeof(float);
    float* H1   = (float*)w;           w += (size_t)NROWS * 128 * sizeof(float);
    float* src1 = (float*)w;           w += (size_t)NROWS * sizeof(float);
    float* dst1 = (float*)w;           w += (size_t)NROWS * sizeof(float);
    float* X1   = (float*)w;           w += (size_t)NROWS * 128 * sizeof(float);
    float* S2   = (float*)w;           w += (size_t)NROWS * 128 * sizeof(float);
    float* H2   = (float*)w;           w += (size_t)NROWS * 64 * sizeof(float);
    float* src2 = (float*)w;           w += (size_t)NROWS * sizeof(float);
    float* dst2 = (float*)w;           w += (size_t)NROWS * sizeof(float);

    // ---- build sparse structure (single adjacency pass) ----
    build_csr<<<NROWS / 4, 256, 0, stream>>>(adj, cnt, col);

    // ---- layer 1 ----
    spmm_sum<256><<<NROWS, 256, 0, stream>>>(cnt, col, feat, S1);
    {
        dim3 g(NROWS / 64, 128 / 64);
        gemm_concat<256, 128><<<g, 256, 0, stream>>>(S1, feat, W0, H1);
    }
    attn_scores<128><<<NROWS / 4, 256, 0, stream>>>(H1, a0, src1, dst1);
    attn_aggregate<128, 0><<<NROWS / 4, 256, 0, stream>>>(cnt, col, H1, src1, dst1, X1);

    // ---- layer 2 ----
    spmm_sum<128><<<NROWS, 128, 0, stream>>>(cnt, col, X1, S2);
    {
        dim3 g(NROWS / 64, 64 / 64);
        gemm_concat<128, 64><<<g, 256, 0, stream>>>(S2, X1, W1, H2);
    }
    attn_scores<64><<<NROWS / 4, 256, 0, stream>>>(H2, a1, src2, dst2);
    attn_aggregate<64, 1><<<NROWS / 4, 256, 0, stream>>>(cnt, col, H2, src2, dst2, out);
}

// Round 2
// 451.551 us; speedup vs baseline: 1.2257x; 1.2257x over previous
//
#include <hip/hip_runtime.h>
#include <math.h>

// Problem constants (from reference): N=8192, F=256, HID=128, C=64
#define NROWS 8192
#define EDGE_CAP 256   // max edges/row; Binomial(8192,0.005) max ~70, 256 is very safe

// ---------------------------------------------------------------------------
// K1: dense adjacency -> fixed-stride CSR (wave per row, ballot compaction)
// ---------------------------------------------------------------------------
__global__ __launch_bounds__(256) void build_csr(const float* __restrict__ adj,
                                                 int* __restrict__ cnt,
                                                 int* __restrict__ col) {
    int row  = blockIdx.x * 4 + (threadIdx.x >> 6);
    int lane = threadIdx.x & 63;
    const float4* arow = (const float4*)(adj + (size_t)row * NROWS);
    int* crow = col + (size_t)row * EDGE_CAP;
    int count = 0;
    for (int it = 0; it < NROWS / 256; ++it) {   // 32 iters: 64 lanes x float4
        float4 v = arow[it * 64 + lane];
        float vv[4] = {v.x, v.y, v.z, v.w};
        #pragma unroll
        for (int p = 0; p < 4; ++p) {
            bool nz = vv[p] > 0.0f;
            unsigned long long m = __ballot(nz);
            if (nz) {
                int off = count + __popcll(m & ((1ull << lane) - 1ull));
                if (off < EDGE_CAP) crow[off] = it * 256 + lane * 4 + p;
            }
            count += __popcll(m);   // wave-uniform
        }
    }
    if (lane == 0) cnt[row] = count < EDGE_CAP ? count : EDGE_CAP;
}

// ---------------------------------------------------------------------------
// K2: [Y | Z] = A @ [W_top || W_bot]  (one dense GEMM, B built by index math)
//   Y = A @ W[0:KD, :]      (goes through the sparse aggregation)
//   Z = A @ W[KD:2KD, :]    (the "self" half of the concat)
// 64x64 tile, 256 threads, 4x4 per thread, fp32
// ---------------------------------------------------------------------------
template <int KD, int FOUT>
__global__ __launch_bounds__(256) void gemm_split(const float* __restrict__ A,
                                                  const float* __restrict__ W,
                                                  float* __restrict__ Y,
                                                  float* __restrict__ Z) {
    const int BK = 16;
    __shared__ float As[BK][64];
    __shared__ float Bs[BK][64];
    int bm = blockIdx.x, bn = blockIdx.y;
    int tid = threadIdx.x;
    int tx = tid & 15, ty = tid >> 4;
    const bool half = (bn * 64) >= FOUT;                    // writing Z half?
    const float* Wb = half ? W + (size_t)KD * FOUT - FOUT : W;
    float acc[4][4] = {};
    for (int k0 = 0; k0 < KD; k0 += BK) {
        {   // A tile: 64 rows x 16 k  (4 threads per row, float4 each)
            int r  = tid >> 2;
            int kk = (tid & 3) * 4;
            float4 v = *(const float4*)&A[(size_t)(bm * 64 + r) * KD + k0 + kk];
            As[kk + 0][r] = v.x; As[kk + 1][r] = v.y;
            As[kk + 2][r] = v.z; As[kk + 3][r] = v.w;
        }
        {   // B tile: 16 k x 64 n
            int kk = tid >> 4;
            int n4 = (tid & 15) * 4;
            *(float4*)&Bs[kk][n4] =
                *(const float4*)&Wb[(size_t)(k0 + kk) * FOUT + bn * 64 + n4];
        }
        __syncthreads();
        #pragma unroll
        for (int kk = 0; kk < BK; ++kk) {
            float a[4], b[4];
            #pragma unroll
            for (int i = 0; i < 4; ++i) a[i] = As[kk][ty * 4 + i];
            #pragma unroll
            for (int i = 0; i < 4; ++i) b[i] = Bs[kk][tx * 4 + i];
            #pragma unroll
            for (int i = 0; i < 4; ++i)
                #pragma unroll
                for (int j = 0; j < 4; ++j) acc[i][j] += a[i] * b[j];
        }
        __syncthreads();
    }
    float* O = half ? Z : Y;
    int col0 = bn * 64 + tx * 4 - (half ? FOUT : 0);
    #pragma unroll
    for (int i = 0; i < 4; ++i) {
        int r = bm * 64 + ty * 4 + i;
        float4 v = {acc[i][0], acc[i][1], acc[i][2], acc[i][3]};
        *(float4*)&O[(size_t)r * FOUT + col0] = v;
    }
}

// ---------------------------------------------------------------------------
// K3: H[i,:] = sum_{j in N(i)} Y[j,:] + Z[i,:]; src/dst attention dots fused.
// wave per row (4 rows / 256-thread block); edge indices staged in LDS;
// gather loop unrolled x4 for memory-level parallelism.
// ---------------------------------------------------------------------------
template <int FOUT>
__global__ __launch_bounds__(256) void spmm_add_scores(const int* __restrict__ cnt,
                                                       const int* __restrict__ col,
                                                       const float* __restrict__ Y,
                                                       const float* __restrict__ Z,
                                                       const float* __restrict__ a,
                                                       float* __restrict__ H,
                                                       float* __restrict__ src,
                                                       float* __restrict__ dst) {
    __shared__ int sbuf[4][EDGE_CAP];
    int wav  = threadIdx.x >> 6;
    int lane = threadIdx.x & 63;
    int row  = blockIdx.x * 4 + wav;
    int n    = cnt[row];
    const int* cr = col + (size_t)row * EDGE_CAP;
    for (int e = lane; e < n; e += 64) sbuf[wav][e] = cr[e];
    // wave-local LDS: all 64 lanes execute the writes before any read below

    float s1, s2;
    if constexpr (FOUT == 128) {
        const float2* Y2 = (const float2*)Y;
        float2 s = {0.0f, 0.0f};
        int e = 0;
        for (; e + 4 <= n; e += 4) {
            int j0 = sbuf[wav][e], j1 = sbuf[wav][e + 1];
            int j2 = sbuf[wav][e + 2], j3 = sbuf[wav][e + 3];
            float2 v0 = Y2[(size_t)j0 * 64 + lane];
            float2 v1 = Y2[(size_t)j1 * 64 + lane];
            float2 v2 = Y2[(size_t)j2 * 64 + lane];
            float2 v3 = Y2[(size_t)j3 * 64 + lane];
            s.x += (v0.x + v1.x) + (v2.x + v3.x);
            s.y += (v0.y + v1.y) + (v2.y + v3.y);
        }
        for (; e < n; ++e) {
            int j = sbuf[wav][e];
            float2 v = Y2[(size_t)j * 64 + lane];
            s.x += v.x; s.y += v.y;
        }
        float2 z = ((const float2*)Z)[(size_t)row * 64 + lane];
        float hx = s.x + z.x, hy = s.y + z.y;
        float2 hv = {hx, hy};
        ((float2*)H)[(size_t)row * 64 + lane] = hv;
        s1 = hx * a[lane * 2] + hy * a[lane * 2 + 1];
        s2 = hx * a[FOUT + lane * 2] + hy * a[FOUT + lane * 2 + 1];
    } else {   // FOUT == 64
        float s = 0.0f;
        int e = 0;
        for (; e + 4 <= n; e += 4) {
            int j0 = sbuf[wav][e], j1 = sbuf[wav][e + 1];
            int j2 = sbuf[wav][e + 2], j3 = sbuf[wav][e + 3];
            float v0 = Y[(size_t)j0 * 64 + lane];
            float v1 = Y[(size_t)j1 * 64 + lane];
            float v2 = Y[(size_t)j2 * 64 + lane];
            float v3 = Y[(size_t)j3 * 64 + lane];
            s += (v0 + v1) + (v2 + v3);
        }
        for (; e < n; ++e) s += Y[(size_t)sbuf[wav][e] * 64 + lane];
        float h = s + Z[(size_t)row * 64 + lane];
        H[(size_t)row * 64 + lane] = h;
        s1 = h * a[lane];
        s2 = h * a[FOUT + lane];
    }
    #pragma unroll
    for (int off = 32; off; off >>= 1) {
        s1 += __shfl_xor(s1, off);
        s2 += __shfl_xor(s2, off);
    }
    if (lane == 0) { src[row] = s1; dst[row] = s2; }
}

// ---------------------------------------------------------------------------
// K4: per-row masked softmax over edges + hp = att @ H, fused epilogue
// MODE 0: ELU (layer 1 output)    MODE 1: log_softmax over 64 classes
// wave per row (4 rows per 256-thread block)
// ---------------------------------------------------------------------------
template <int FOUT, int MODE>
__global__ __launch_bounds__(256) void attn_aggregate(const int* __restrict__ cnt,
                                                      const int* __restrict__ col,
                                                      const float* __restrict__ H,
                                                      const float* __restrict__ src,
                                                      const float* __restrict__ dst,
                                                      float* __restrict__ out) {
    __shared__ float pbuf[4][EDGE_CAP];
    __shared__ int   cbuf[4][EDGE_CAP];
    int wav  = threadIdx.x >> 6;
    int lane = threadIdx.x & 63;
    int row  = blockIdx.x * 4 + wav;
    int n    = cnt[row];
    const int* cr = col + (size_t)row * EDGE_CAP;
    float si = src[row];

    // pass 1: e = leaky_relu(src_i + dst_j), row max
    float m = -3.0e38f;
    for (int e = lane; e < n; e += 64) {
        int j = cr[e];
        float x = si + dst[j];
        x = x > 0.0f ? x : 0.2f * x;
        cbuf[wav][e] = j;
        pbuf[wav][e] = x;
        m = fmaxf(m, x);
    }
    #pragma unroll
    for (int off = 32; off; off >>= 1) m = fmaxf(m, __shfl_xor(m, off));

    // pass 2: exp, row sum  (non-edges contribute exp(-9e15 - m) == 0 exactly)
    float ssum = 0.0f;
    for (int e = lane; e < n; e += 64) {
        float p = __expf(pbuf[wav][e] - m);
        pbuf[wav][e] = p;
        ssum += p;
    }
    #pragma unroll
    for (int off = 32; off; off >>= 1) ssum += __shfl_xor(ssum, off);
    float inv = 1.0f / ssum;

    // pass 3: hp[i,c] = (1/sum) * sum_e p_e * H[j_e, c]; lanes = columns
    if constexpr (FOUT == 128) {
        const float2* H2 = (const float2*)H;
        float2 o = {0.0f, 0.0f};
        int e = 0;
        for (; e + 4 <= n; e += 4) {
            int j0 = cbuf[wav][e], j1 = cbuf[wav][e + 1];
            int j2 = cbuf[wav][e + 2], j3 = cbuf[wav][e + 3];
            float p0 = pbuf[wav][e],     p1 = pbuf[wav][e + 1];
            float p2 = pbuf[wav][e + 2], p3 = pbuf[wav][e + 3];
            float2 v0 = H2[(size_t)j0 * 64 + lane];
            float2 v1 = H2[(size_t)j1 * 64 + lane];
            float2 v2 = H2[(size_t)j2 * 64 + lane];
            float2 v3 = H2[(size_t)j3 * 64 + lane];
            o.x += (p0 * v0.x + p1 * v1.x) + (p2 * v2.x + p3 * v3.x);
            o.y += (p0 * v0.y + p1 * v1.y) + (p2 * v2.y + p3 * v3.y);
        }
        for (; e < n; ++e) {
            int j = cbuf[wav][e];
            float p = pbuf[wav][e];
            float2 v = H2[(size_t)j * 64 + lane];
            o.x += p * v.x; o.y += p * v.y;
        }
        float vx = o.x * inv, vy = o.y * inv;
        vx = vx > 0.0f ? vx : (__expf(vx) - 1.0f);   // ELU, alpha=1
        vy = vy > 0.0f ? vy : (__expf(vy) - 1.0f);
        float2 ov = {vx, vy};
        ((float2*)out)[(size_t)row * 64 + lane] = ov;
    } else {   // FOUT == 64, MODE == 1
        float o = 0.0f;
        int e = 0;
        for (; e + 4 <= n; e += 4) {
            int j0 = cbuf[wav][e], j1 = cbuf[wav][e + 1];
            int j2 = cbuf[wav][e + 2], j3 = cbuf[wav][e + 3];
            float p0 = pbuf[wav][e],     p1 = pbuf[wav][e + 1];
            float p2 = pbuf[wav][e + 2], p3 = pbuf[wav][e + 3];
            float v0 = H[(size_t)j0 * 64 + lane];
            float v1 = H[(size_t)j1 * 64 + lane];
            float v2 = H[(size_t)j2 * 64 + lane];
            float v3 = H[(size_t)j3 * 64 + lane];
            o += (p0 * v0 + p1 * v1) + (p2 * v2 + p3 * v3);
        }
        for (; e < n; ++e) o += pbuf[wav][e] * H[(size_t)cbuf[wav][e] * 64 + lane];
        // one class per lane; fused log_softmax across the wave
        float logit = o * inv;
        float mm = logit;
        #pragma unroll
        for (int off = 32; off; off >>= 1) mm = fmaxf(mm, __shfl_xor(mm, off));
        float se = __expf(logit - mm);
        #pragma unroll
        for (int off = 32; off; off >>= 1) se += __shfl_xor(se, off);
        out[(size_t)row * 64 + lane] = logit - mm - logf(se);
    }
}

// ---------------------------------------------------------------------------
extern "C" void kernel_launch(void* const* d_in, const int* in_sizes, int n_in,
                              void* d_out, int out_size, void* d_ws, size_t ws_size,
                              hipStream_t stream) {
    const float* feat = (const float*)d_in[0];   // (8192, 256)
    const float* adj  = (const float*)d_in[1];   // (8192, 8192)
    const float* W0   = (const float*)d_in[2];   // (512, 128)
    const float* a0   = (const float*)d_in[3];   // (256,)
    const float* W1   = (const float*)d_in[4];   // (256, 64)
    const float* a1   = (const float*)d_in[5];   // (128,)
    float* out = (float*)d_out;                  // (8192, 64)

    // workspace layout (~31 MB total)
    char* w = (char*)d_ws;
    int* cnt = (int*)w;                w += (size_t)NROWS * sizeof(int);
    int* col = (int*)w;                w += (size_t)NROWS * EDGE_CAP * sizeof(int);
    float* Y1   = (float*)w;           w += (size_t)NROWS * 128 * sizeof(float);
    float* Z1   = (float*)w;           w += (size_t)NROWS * 128 * sizeof(float);
    float* H1   = (float*)w;           w += (size_t)NROWS * 128 * sizeof(float);
    float* src1 = (float*)w;           w += (size_t)NROWS * sizeof(float);
    float* dst1 = (float*)w;           w += (size_t)NROWS * sizeof(float);
    float* X1   = (float*)w;           w += (size_t)NROWS * 128 * sizeof(float);
    float* Y2   = (float*)w;           w += (size_t)NROWS * 64 * sizeof(float);
    float* Z2   = (float*)w;           w += (size_t)NROWS * 64 * sizeof(float);
    float* H2   = (float*)w;           w += (size_t)NROWS * 64 * sizeof(float);
    float* src2 = (float*)w;           w += (size_t)NROWS * sizeof(float);
    float* dst2 = (float*)w;           w += (size_t)NROWS * sizeof(float);

    // ---- sparse structure (single adjacency pass) ----
    build_csr<<<NROWS / 4, 256, 0, stream>>>(adj, cnt, col);

    // ---- layer 1:  H1 = adj@(feat@W0_top) + feat@W0_bot ----
    {
        dim3 g(NROWS / 64, 2 * 128 / 64);
        gemm_split<256, 128><<<g, 256, 0, stream>>>(feat, W0, Y1, Z1);
    }
    spmm_add_scores<128><<<NROWS / 4, 256, 0, stream>>>(cnt, col, Y1, Z1, a0, H1, src1, dst1);
    attn_aggregate<128, 0><<<NROWS / 4, 256, 0, stream>>>(cnt, col, H1, src1, dst1, X1);

    // ---- layer 2 ----
    {
        dim3 g(NROWS / 64, 2 * 64 / 64);
        gemm_split<128, 64><<<g, 256, 0, stream>>>(X1, W1, Y2, Z2);
    }
    spmm_add_scores<64><<<NROWS / 4, 256, 0, stream>>>(cnt, col, Y2, Z2, a1, H2, src2, dst2);
    attn_aggregate<64, 1><<<NROWS / 4, 256, 0, stream>>>(cnt, col, H2, src2, dst2, out);
}

// Round 3
// 438.152 us; speedup vs baseline: 1.2631x; 1.0306x over previous
//
#include <hip/hip_runtime.h>
#include <math.h>

// Problem constants (from reference): N=8192, F=256, HID=128, C=64
#define NROWS 8192
#define EDGE_CAP 128   // max row degree ~70 (Binomial(8192,0.005)); 128 is safe

// ---------------------------------------------------------------------------
// K1 (fused, heterogeneous): blocks [0,256)   : Y|Z = feat @ [W0_top || W0_bot]
//                            blocks [256,2304): dense adj -> fixed-stride CSR
// The two halves are independent; fusing overlaps HBM-bound CSR scan with
// LDS/VALU-bound GEMM.
// ---------------------------------------------------------------------------
__global__ __launch_bounds__(256) void fused_csr_gemm1(const float* __restrict__ adj,
                                                       int* __restrict__ cnt,
                                                       int* __restrict__ col,
                                                       const float* __restrict__ A,
                                                       const float* __restrict__ W,
                                                       float* __restrict__ Y,
                                                       float* __restrict__ Z) {
    __shared__ float As[16][64];     // 4 KB
    __shared__ float Bs[16][128];    // 8 KB
    int gb  = blockIdx.x;
    int tid = threadIdx.x;

    if (gb < 256) {
        // ---- GEMM role: BM=64, BN=128, K=256; 4x8 per thread ----
        int bm = gb & 127, bn = gb >> 7;          // bn=0 -> Y, bn=1 -> Z
        int tx = tid & 15, ty = tid >> 4;
        const float* Wb = W + (size_t)bn * 256 * 128;
        float acc[4][8] = {};
        for (int k0 = 0; k0 < 256; k0 += 16) {
            {   // A tile 64x16
                int r = tid >> 2, kk = (tid & 3) * 4;
                float4 v = *(const float4*)&A[(size_t)(bm * 64 + r) * 256 + k0 + kk];
                As[kk + 0][r] = v.x; As[kk + 1][r] = v.y;
                As[kk + 2][r] = v.z; As[kk + 3][r] = v.w;
            }
            {   // B tile 16x128
                int kk = tid >> 4, c = (tid & 15) * 8;
                *(float4*)&Bs[kk][c]     = *(const float4*)&Wb[(size_t)(k0 + kk) * 128 + c];
                *(float4*)&Bs[kk][c + 4] = *(const float4*)&Wb[(size_t)(k0 + kk) * 128 + c + 4];
            }
            __syncthreads();
            #pragma unroll
            for (int kk = 0; kk < 16; ++kk) {
                float a[4], b[8];
                #pragma unroll
                for (int i = 0; i < 4; ++i) a[i] = As[kk][ty * 4 + i];
                #pragma unroll
                for (int j = 0; j < 8; ++j) b[j] = Bs[kk][tx * 8 + j];
                #pragma unroll
                for (int i = 0; i < 4; ++i)
                    #pragma unroll
                    for (int j = 0; j < 8; ++j) acc[i][j] += a[i] * b[j];
            }
            __syncthreads();
        }
        float* O = bn ? Z : Y;
        #pragma unroll
        for (int i = 0; i < 4; ++i) {
            int r = bm * 64 + ty * 4 + i;
            float4 v0 = {acc[i][0], acc[i][1], acc[i][2], acc[i][3]};
            float4 v1 = {acc[i][4], acc[i][5], acc[i][6], acc[i][7]};
            *(float4*)&O[(size_t)r * 128 + tx * 8]     = v0;
            *(float4*)&O[(size_t)r * 128 + tx * 8 + 4] = v1;
        }
    } else {
        // ---- CSR role: wave per row, ballot compaction ----
        int row  = (gb - 256) * 4 + (tid >> 6);
        int lane = tid & 63;
        const float4* arow = (const float4*)(adj + (size_t)row * NROWS);
        int* crow = col + (size_t)row * EDGE_CAP;
        int count = 0;
        for (int it = 0; it < NROWS / 256; ++it) {   // 32 iters: 64 lanes x float4
            float4 v = arow[it * 64 + lane];
            float vv[4] = {v.x, v.y, v.z, v.w};
            #pragma unroll
            for (int p = 0; p < 4; ++p) {
                bool nz = vv[p] > 0.0f;
                unsigned long long m = __ballot(nz);
                if (nz) {
                    int off = count + __popcll(m & ((1ull << lane) - 1ull));
                    if (off < EDGE_CAP) crow[off] = it * 256 + lane * 4 + p;
                }
                count += __popcll(m);   // wave-uniform
            }
        }
        if (lane == 0) cnt[row] = count < EDGE_CAP ? count : EDGE_CAP;
    }
}

// ---------------------------------------------------------------------------
// K2 (layer 2 only): [Y | Z] = A @ [W_top || W_bot], 64x64 tile, 4x4/thread
// ---------------------------------------------------------------------------
template <int KD, int FOUT>
__global__ __launch_bounds__(256) void gemm_split(const float* __restrict__ A,
                                                  const float* __restrict__ W,
                                                  float* __restrict__ Y,
                                                  float* __restrict__ Z) {
    const int BK = 16;
    __shared__ float As[BK][64];
    __shared__ float Bs[BK][64];
    int bm = blockIdx.x, bn = blockIdx.y;
    int tid = threadIdx.x;
    int tx = tid & 15, ty = tid >> 4;
    const bool half = (bn * 64) >= FOUT;                    // writing Z half?
    const float* Wb = half ? W + (size_t)KD * FOUT - FOUT : W;
    float acc[4][4] = {};
    for (int k0 = 0; k0 < KD; k0 += BK) {
        {   // A tile: 64 rows x 16 k
            int r  = tid >> 2;
            int kk = (tid & 3) * 4;
            float4 v = *(const float4*)&A[(size_t)(bm * 64 + r) * KD + k0 + kk];
            As[kk + 0][r] = v.x; As[kk + 1][r] = v.y;
            As[kk + 2][r] = v.z; As[kk + 3][r] = v.w;
        }
        {   // B tile: 16 k x 64 n
            int kk = tid >> 4;
            int n4 = (tid & 15) * 4;
            *(float4*)&Bs[kk][n4] =
                *(const float4*)&Wb[(size_t)(k0 + kk) * FOUT + bn * 64 + n4];
        }
        __syncthreads();
        #pragma unroll
        for (int kk = 0; kk < BK; ++kk) {
            float a[4], b[4];
            #pragma unroll
            for (int i = 0; i < 4; ++i) a[i] = As[kk][ty * 4 + i];
            #pragma unroll
            for (int i = 0; i < 4; ++i) b[i] = Bs[kk][tx * 4 + i];
            #pragma unroll
            for (int i = 0; i < 4; ++i)
                #pragma unroll
                for (int j = 0; j < 4; ++j) acc[i][j] += a[i] * b[j];
        }
        __syncthreads();
    }
    float* O = half ? Z : Y;
    int col0 = bn * 64 + tx * 4 - (half ? FOUT : 0);
    #pragma unroll
    for (int i = 0; i < 4; ++i) {
        int r = bm * 64 + ty * 4 + i;
        float4 v = {acc[i][0], acc[i][1], acc[i][2], acc[i][3]};
        *(float4*)&O[(size_t)r * FOUT + col0] = v;
    }
}

// ---------------------------------------------------------------------------
// K3: H[i,:] = sum_{j in N(i)} Y[j,:] + Z[i,:]; src/dst attention dots fused.
// wave per row; edges staged in LDS; gather loop unrolled x8 for MLP.
// ---------------------------------------------------------------------------
template <int FOUT>
__global__ __launch_bounds__(256) void spmm_add_scores(const int* __restrict__ cnt,
                                                       const int* __restrict__ col,
                                                       const float* __restrict__ Y,
                                                       const float* __restrict__ Z,
                                                       const float* __restrict__ a,
                                                       float* __restrict__ H,
                                                       float* __restrict__ src,
                                                       float* __restrict__ dst) {
    __shared__ int sbuf[4][EDGE_CAP];
    int wav  = threadIdx.x >> 6;
    int lane = threadIdx.x & 63;
    int row  = blockIdx.x * 4 + wav;
    int n    = cnt[row];
    const int* cr = col + (size_t)row * EDGE_CAP;
    for (int e = lane; e < n; e += 64) sbuf[wav][e] = cr[e];
    // wave-local LDS: writes by this wave precede reads by this wave

    float s1, s2;
    if constexpr (FOUT == 128) {
        const float2* Y2 = (const float2*)Y;
        float2 s = {0.0f, 0.0f};
        int e = 0;
        for (; e + 8 <= n; e += 8) {
            float2 v[8];
            #pragma unroll
            for (int u = 0; u < 8; ++u) {
                int j = sbuf[wav][e + u];
                v[u] = Y2[(size_t)j * 64 + lane];
            }
            #pragma unroll
            for (int u = 0; u < 8; ++u) { s.x += v[u].x; s.y += v[u].y; }
        }
        for (; e < n; ++e) {
            int j = sbuf[wav][e];
            float2 v = Y2[(size_t)j * 64 + lane];
            s.x += v.x; s.y += v.y;
        }
        float2 z = ((const float2*)Z)[(size_t)row * 64 + lane];
        float hx = s.x + z.x, hy = s.y + z.y;
        float2 hv = {hx, hy};
        ((float2*)H)[(size_t)row * 64 + lane] = hv;
        s1 = hx * a[lane * 2] + hy * a[lane * 2 + 1];
        s2 = hx * a[FOUT + lane * 2] + hy * a[FOUT + lane * 2 + 1];
    } else {   // FOUT == 64
        float s = 0.0f;
        int e = 0;
        for (; e + 8 <= n; e += 8) {
            float v[8];
            #pragma unroll
            for (int u = 0; u < 8; ++u) v[u] = Y[(size_t)sbuf[wav][e + u] * 64 + lane];
            #pragma unroll
            for (int u = 0; u < 8; ++u) s += v[u];
        }
        for (; e < n; ++e) s += Y[(size_t)sbuf[wav][e] * 64 + lane];
        float h = s + Z[(size_t)row * 64 + lane];
        H[(size_t)row * 64 + lane] = h;
        s1 = h * a[lane];
        s2 = h * a[FOUT + lane];
    }
    #pragma unroll
    for (int off = 32; off; off >>= 1) {
        s1 += __shfl_xor(s1, off);
        s2 += __shfl_xor(s2, off);
    }
    if (lane == 0) { src[row] = s1; dst[row] = s2; }
}

// ---------------------------------------------------------------------------
// K4: per-row masked softmax over edges + hp = att @ H, fused epilogue
// MODE 0: ELU (layer 1 output)    MODE 1: log_softmax over 64 classes
// ---------------------------------------------------------------------------
template <int FOUT, int MODE>
__global__ __launch_bounds__(256) void attn_aggregate(const int* __restrict__ cnt,
                                                      const int* __restrict__ col,
                                                      const float* __restrict__ H,
                                                      const float* __restrict__ src,
                                                      const float* __restrict__ dst,
                                                      float* __restrict__ out) {
    __shared__ float pbuf[4][EDGE_CAP];
    __shared__ int   cbuf[4][EDGE_CAP];
    int wav  = threadIdx.x >> 6;
    int lane = threadIdx.x & 63;
    int row  = blockIdx.x * 4 + wav;
    int n    = cnt[row];
    const int* cr = col + (size_t)row * EDGE_CAP;
    float si = src[row];

    // pass 1: e = leaky_relu(src_i + dst_j), row max (n <= 128 -> <= 2 iters)
    float m = -3.0e38f;
    for (int e = lane; e < n; e += 64) {
        int j = cr[e];
        float x = si + dst[j];
        x = x > 0.0f ? x : 0.2f * x;
        cbuf[wav][e] = j;
        pbuf[wav][e] = x;
        m = fmaxf(m, x);
    }
    #pragma unroll
    for (int off = 32; off; off >>= 1) m = fmaxf(m, __shfl_xor(m, off));

    // pass 2: exp, row sum  (non-edges contribute exp(-9e15 - m) == 0 exactly)
    float ssum = 0.0f;
    for (int e = lane; e < n; e += 64) {
        float p = __expf(pbuf[wav][e] - m);
        pbuf[wav][e] = p;
        ssum += p;
    }
    #pragma unroll
    for (int off = 32; off; off >>= 1) ssum += __shfl_xor(ssum, off);
    float inv = 1.0f / ssum;

    // pass 3: hp[i,c] = (1/sum) * sum_e p_e * H[j_e, c]; lanes = columns
    if constexpr (FOUT == 128) {
        const float2* H2 = (const float2*)H;
        float2 o = {0.0f, 0.0f};
        int e = 0;
        for (; e + 8 <= n; e += 8) {
            float2 v[8]; float p[8];
            #pragma unroll
            for (int u = 0; u < 8; ++u) {
                int j = cbuf[wav][e + u];
                p[u] = pbuf[wav][e + u];
                v[u] = H2[(size_t)j * 64 + lane];
            }
            #pragma unroll
            for (int u = 0; u < 8; ++u) { o.x += p[u] * v[u].x; o.y += p[u] * v[u].y; }
        }
        for (; e < n; ++e) {
            int j = cbuf[wav][e];
            float p = pbuf[wav][e];
            float2 v = H2[(size_t)j * 64 + lane];
            o.x += p * v.x; o.y += p * v.y;
        }
        float vx = o.x * inv, vy = o.y * inv;
        vx = vx > 0.0f ? vx : (__expf(vx) - 1.0f);   // ELU, alpha=1
        vy = vy > 0.0f ? vy : (__expf(vy) - 1.0f);
        float2 ov = {vx, vy};
        ((float2*)out)[(size_t)row * 64 + lane] = ov;
    } else {   // FOUT == 64, MODE == 1
        float o = 0.0f;
        int e = 0;
        for (; e + 8 <= n; e += 8) {
            float v[8]; float p[8];
            #pragma unroll
            for (int u = 0; u < 8; ++u) {
                p[u] = pbuf[wav][e + u];
                v[u] = H[(size_t)cbuf[wav][e + u] * 64 + lane];
            }
            #pragma unroll
            for (int u = 0; u < 8; ++u) o += p[u] * v[u];
        }
        for (; e < n; ++e) o += pbuf[wav][e] * H[(size_t)cbuf[wav][e] * 64 + lane];
        // one class per lane; fused log_softmax across the wave
        float logit = o * inv;
        float mm = logit;
        #pragma unroll
        for (int off = 32; off; off >>= 1) mm = fmaxf(mm, __shfl_xor(mm, off));
        float se = __expf(logit - mm);
        #pragma unroll
        for (int off = 32; off; off >>= 1) se += __shfl_xor(se, off);
        out[(size_t)row * 64 + lane] = logit - mm - logf(se);
    }
}

// ---------------------------------------------------------------------------
extern "C" void kernel_launch(void* const* d_in, const int* in_sizes, int n_in,
                              void* d_out, int out_size, void* d_ws, size_t ws_size,
                              hipStream_t stream) {
    const float* feat = (const float*)d_in[0];   // (8192, 256)
    const float* adj  = (const float*)d_in[1];   // (8192, 8192)
    const float* W0   = (const float*)d_in[2];   // (512, 128)
    const float* a0   = (const float*)d_in[3];   // (256,)
    const float* W1   = (const float*)d_in[4];   // (256, 64)
    const float* a1   = (const float*)d_in[5];   // (128,)
    float* out = (float*)d_out;                  // (8192, 64)

    // workspace layout (~27 MB total)
    char* w = (char*)d_ws;
    int* cnt = (int*)w;                w += (size_t)NROWS * sizeof(int);
    int* col = (int*)w;                w += (size_t)NROWS * EDGE_CAP * sizeof(int);
    float* Y1   = (float*)w;           w += (size_t)NROWS * 128 * sizeof(float);
    float* Z1   = (float*)w;           w += (size_t)NROWS * 128 * sizeof(float);
    float* H1   = (float*)w;           w += (size_t)NROWS * 128 * sizeof(float);
    float* src1 = (float*)w;           w += (size_t)NROWS * sizeof(float);
    float* dst1 = (float*)w;           w += (size_t)NROWS * sizeof(float);
    float* X1   = (float*)w;           w += (size_t)NROWS * 128 * sizeof(float);
    float* Y2   = (float*)w;           w += (size_t)NROWS * 64 * sizeof(float);
    float* Z2   = (float*)w;           w += (size_t)NROWS * 64 * sizeof(float);
    float* H2   = (float*)w;           w += (size_t)NROWS * 64 * sizeof(float);
    float* src2 = (float*)w;           w += (size_t)NROWS * sizeof(float);
    float* dst2 = (float*)w;           w += (size_t)NROWS * sizeof(float);

    // ---- fused: CSR build (blocks 256..2303) + layer-1 GEMM (blocks 0..255) ----
    fused_csr_gemm1<<<256 + NROWS / 4, 256, 0, stream>>>(adj, cnt, col, feat, W0, Y1, Z1);

    // ---- layer 1:  H1 = adj@(feat@W0_top) + feat@W0_bot, scores, aggregate ----
    spmm_add_scores<128><<<NROWS / 4, 256, 0, stream>>>(cnt, col, Y1, Z1, a0, H1, src1, dst1);
    attn_aggregate<128, 0><<<NROWS / 4, 256, 0, stream>>>(cnt, col, H1, src1, dst1, X1);

    // ---- layer 2 ----
    {
        dim3 g(NROWS / 64, 2 * 64 / 64);
        gemm_split<128, 64><<<g, 256, 0, stream>>>(X1, W1, Y2, Z2);
    }
    spmm_add_scores<64><<<NROWS / 4, 256, 0, stream>>>(cnt, col, Y2, Z2, a1, H2, src2, dst2);
    attn_aggregate<64, 1><<<NROWS / 4, 256, 0, stream>>>(cnt, col, H2, src2, dst2, out);
}

// Round 4
// 432.491 us; speedup vs baseline: 1.2797x; 1.0131x over previous
//
#include <hip/hip_runtime.h>
#include <math.h>

// Problem constants (from reference): N=8192, F=256, HID=128, C=64
#define NROWS 8192
#define EDGE_CAP 128   // max row degree ~70 (Binomial(8192,0.005)); 128 is safe

using f4v = __attribute__((ext_vector_type(4))) float;

// ---------------------------------------------------------------------------
// K1 (fused, heterogeneous): blocks [0,256)   : Y|Z = feat @ [W0_top || W0_bot]
//                            blocks [256,2304): dense adj -> fixed-stride CSR
// CSR scan uses non-temporal loads: adj is read-once, keep it out of L2 so the
// co-resident GEMM's tiles stay cached.
// ---------------------------------------------------------------------------
__global__ __launch_bounds__(256) void fused_csr_gemm1(const float* __restrict__ adj,
                                                       int* __restrict__ cnt,
                                                       int* __restrict__ col,
                                                       const float* __restrict__ A,
                                                       const float* __restrict__ W,
                                                       float* __restrict__ Y,
                                                       float* __restrict__ Z) {
    __shared__ float As[16][64];     // 4 KB
    __shared__ float Bs[16][128];    // 8 KB
    int gb  = blockIdx.x;
    int tid = threadIdx.x;

    if (gb < 256) {
        // ---- GEMM role: BM=64, BN=128, K=256; 4x8 per thread ----
        int bm = gb & 127, bn = gb >> 7;          // bn=0 -> Y, bn=1 -> Z
        int tx = tid & 15, ty = tid >> 4;
        const float* Wb = W + (size_t)bn * 256 * 128;
        float acc[4][8] = {};
        for (int k0 = 0; k0 < 256; k0 += 16) {
            {   // A tile 64x16
                int r = tid >> 2, kk = (tid & 3) * 4;
                float4 v = *(const float4*)&A[(size_t)(bm * 64 + r) * 256 + k0 + kk];
                As[kk + 0][r] = v.x; As[kk + 1][r] = v.y;
                As[kk + 2][r] = v.z; As[kk + 3][r] = v.w;
            }
            {   // B tile 16x128
                int kk = tid >> 4, c = (tid & 15) * 8;
                *(float4*)&Bs[kk][c]     = *(const float4*)&Wb[(size_t)(k0 + kk) * 128 + c];
                *(float4*)&Bs[kk][c + 4] = *(const float4*)&Wb[(size_t)(k0 + kk) * 128 + c + 4];
            }
            __syncthreads();
            #pragma unroll
            for (int kk = 0; kk < 16; ++kk) {
                float a[4], b[8];
                #pragma unroll
                for (int i = 0; i < 4; ++i) a[i] = As[kk][ty * 4 + i];
                #pragma unroll
                for (int j = 0; j < 8; ++j) b[j] = Bs[kk][tx * 8 + j];
                #pragma unroll
                for (int i = 0; i < 4; ++i)
                    #pragma unroll
                    for (int j = 0; j < 8; ++j) acc[i][j] += a[i] * b[j];
            }
            __syncthreads();
        }
        float* O = bn ? Z : Y;
        #pragma unroll
        for (int i = 0; i < 4; ++i) {
            int r = bm * 64 + ty * 4 + i;
            float4 v0 = {acc[i][0], acc[i][1], acc[i][2], acc[i][3]};
            float4 v1 = {acc[i][4], acc[i][5], acc[i][6], acc[i][7]};
            *(float4*)&O[(size_t)r * 128 + tx * 8]     = v0;
            *(float4*)&O[(size_t)r * 128 + tx * 8 + 4] = v1;
        }
    } else {
        // ---- CSR role: wave per row, ballot compaction ----
        int row  = (gb - 256) * 4 + (tid >> 6);
        int lane = tid & 63;
        const f4v* arow = (const f4v*)(adj + (size_t)row * NROWS);
        int* crow = col + (size_t)row * EDGE_CAP;
        int count = 0;
        for (int it = 0; it < NROWS / 256; ++it) {   // 32 iters: 64 lanes x float4
            f4v v = __builtin_nontemporal_load(&arow[it * 64 + lane]);
            float vv[4] = {v.x, v.y, v.z, v.w};
            #pragma unroll
            for (int p = 0; p < 4; ++p) {
                bool nz = vv[p] > 0.0f;
                unsigned long long m = __ballot(nz);
                if (nz) {
                    int off = count + __popcll(m & ((1ull << lane) - 1ull));
                    if (off < EDGE_CAP) crow[off] = it * 256 + lane * 4 + p;
                }
                count += __popcll(m);   // wave-uniform
            }
        }
        if (lane == 0) cnt[row] = count < EDGE_CAP ? count : EDGE_CAP;
    }
}

// ---------------------------------------------------------------------------
// K2: H[i,:] = sum_{j in N(i)} Y[j,:] + Z[i,:]; src/dst attention dots fused.
// wave per row; edges staged in LDS; gather loop unrolled x8 for MLP.
// ---------------------------------------------------------------------------
template <int FOUT>
__global__ __launch_bounds__(256) void spmm_add_scores(const int* __restrict__ cnt,
                                                       const int* __restrict__ col,
                                                       const float* __restrict__ Y,
                                                       const float* __restrict__ Z,
                                                       const float* __restrict__ a,
                                                       float* __restrict__ H,
                                                       float* __restrict__ src,
                                                       float* __restrict__ dst) {
    __shared__ int sbuf[4][EDGE_CAP];
    int wav  = threadIdx.x >> 6;
    int lane = threadIdx.x & 63;
    int row  = blockIdx.x * 4 + wav;
    int n    = cnt[row];
    const int* cr = col + (size_t)row * EDGE_CAP;
    for (int e = lane; e < n; e += 64) sbuf[wav][e] = cr[e];
    // wave-local LDS: writes by this wave precede reads by this wave

    float s1, s2;
    if constexpr (FOUT == 128) {
        const float2* Y2 = (const float2*)Y;
        float2 s = {0.0f, 0.0f};
        int e = 0;
        for (; e + 8 <= n; e += 8) {
            float2 v[8];
            #pragma unroll
            for (int u = 0; u < 8; ++u) {
                int j = sbuf[wav][e + u];
                v[u] = Y2[(size_t)j * 64 + lane];
            }
            #pragma unroll
            for (int u = 0; u < 8; ++u) { s.x += v[u].x; s.y += v[u].y; }
        }
        for (; e < n; ++e) {
            int j = sbuf[wav][e];
            float2 v = Y2[(size_t)j * 64 + lane];
            s.x += v.x; s.y += v.y;
        }
        float2 z = ((const float2*)Z)[(size_t)row * 64 + lane];
        float hx = s.x + z.x, hy = s.y + z.y;
        float2 hv = {hx, hy};
        ((float2*)H)[(size_t)row * 64 + lane] = hv;
        s1 = hx * a[lane * 2] + hy * a[lane * 2 + 1];
        s2 = hx * a[FOUT + lane * 2] + hy * a[FOUT + lane * 2 + 1];
    } else {   // FOUT == 64
        float s = 0.0f;
        int e = 0;
        for (; e + 8 <= n; e += 8) {
            float v[8];
            #pragma unroll
            for (int u = 0; u < 8; ++u) v[u] = Y[(size_t)sbuf[wav][e + u] * 64 + lane];
            #pragma unroll
            for (int u = 0; u < 8; ++u) s += v[u];
        }
        for (; e < n; ++e) s += Y[(size_t)sbuf[wav][e] * 64 + lane];
        float h = s + Z[(size_t)row * 64 + lane];
        H[(size_t)row * 64 + lane] = h;
        s1 = h * a[lane];
        s2 = h * a[FOUT + lane];
    }
    #pragma unroll
    for (int off = 32; off; off >>= 1) {
        s1 += __shfl_xor(s1, off);
        s2 += __shfl_xor(s2, off);
    }
    if (lane == 0) { src[row] = s1; dst[row] = s2; }
}

// ---------------------------------------------------------------------------
// K3: layer-1 softmax-aggregate + ELU + fused layer-2 GEMM.
// The wave holding row i's X1 (post-ELU) stages it in LDS and computes
// Y2[i,:] = X1[i,:] @ W1[0:128,:], Z2[i,:] = X1[i,:] @ W1[128:256,:]
// directly (lane = output column). X1 is never materialized in global.
// Accumulation order over k matches the old tiled GEMM (ascending).
// ---------------------------------------------------------------------------
__global__ __launch_bounds__(256) void attn_agg_gemm2(const int* __restrict__ cnt,
                                                      const int* __restrict__ col,
                                                      const float* __restrict__ H,
                                                      const float* __restrict__ src,
                                                      const float* __restrict__ dst,
                                                      const float* __restrict__ W1,
                                                      float* __restrict__ Y2,
                                                      float* __restrict__ Z2) {
    __shared__ float pbuf[4][EDGE_CAP];
    __shared__ int   cbuf[4][EDGE_CAP];
    __shared__ float xrow[4][128];
    int wav  = threadIdx.x >> 6;
    int lane = threadIdx.x & 63;
    int row  = blockIdx.x * 4 + wav;
    int n    = cnt[row];
    const int* cr = col + (size_t)row * EDGE_CAP;
    float si = src[row];

    // pass 1: e = leaky_relu(src_i + dst_j), row max (n <= 128 -> <= 2 iters)
    float m = -3.0e38f;
    for (int e = lane; e < n; e += 64) {
        int j = cr[e];
        float x = si + dst[j];
        x = x > 0.0f ? x : 0.2f * x;
        cbuf[wav][e] = j;
        pbuf[wav][e] = x;
        m = fmaxf(m, x);
    }
    #pragma unroll
    for (int off = 32; off; off >>= 1) m = fmaxf(m, __shfl_xor(m, off));

    // pass 2: exp, row sum  (non-edges contribute exp(-9e15 - m) == 0 exactly)
    float ssum = 0.0f;
    for (int e = lane; e < n; e += 64) {
        float p = __expf(pbuf[wav][e] - m);
        pbuf[wav][e] = p;
        ssum += p;
    }
    #pragma unroll
    for (int off = 32; off; off >>= 1) ssum += __shfl_xor(ssum, off);
    float inv = 1.0f / ssum;

    // pass 3: hp[i,c] = (1/sum) * sum_e p_e * H[j_e, c]; lanes = column pairs
    const float2* H2 = (const float2*)H;
    float2 o = {0.0f, 0.0f};
    int e = 0;
    for (; e + 8 <= n; e += 8) {
        float2 v[8]; float p[8];
        #pragma unroll
        for (int u = 0; u < 8; ++u) {
            int j = cbuf[wav][e + u];
            p[u] = pbuf[wav][e + u];
            v[u] = H2[(size_t)j * 64 + lane];
        }
        #pragma unroll
        for (int u = 0; u < 8; ++u) { o.x += p[u] * v[u].x; o.y += p[u] * v[u].y; }
    }
    for (; e < n; ++e) {
        int j = cbuf[wav][e];
        float p = pbuf[wav][e];
        float2 v = H2[(size_t)j * 64 + lane];
        o.x += p * v.x; o.y += p * v.y;
    }
    float vx = o.x * inv, vy = o.y * inv;
    vx = vx > 0.0f ? vx : (__expf(vx) - 1.0f);   // ELU, alpha=1
    vy = vy > 0.0f ? vy : (__expf(vy) - 1.0f);

    // stage X1 row in LDS (wave-local; lane holds cols 2*lane, 2*lane+1)
    float2 hv = {vx, vy};
    ((float2*)&xrow[wav][0])[lane] = hv;

    // fused layer-2 GEMV: lane = output column c
    float y = 0.0f, z = 0.0f;
    #pragma unroll 8
    for (int k = 0; k < 128; ++k) {
        float xk = xrow[wav][k];                       // LDS broadcast (free)
        y += xk * W1[(size_t)k * 64 + lane];           // W1 top half (rows 0..127)
        z += xk * W1[(size_t)(128 + k) * 64 + lane];   // W1 bottom half
    }
    Y2[(size_t)row * 64 + lane] = y;
    Z2[(size_t)row * 64 + lane] = z;
}

// ---------------------------------------------------------------------------
// K4: layer-2 softmax-aggregate + fused log_softmax (64 classes, lane=class)
// ---------------------------------------------------------------------------
__global__ __launch_bounds__(256) void attn_agg_final(const int* __restrict__ cnt,
                                                      const int* __restrict__ col,
                                                      const float* __restrict__ H,
                                                      const float* __restrict__ src,
                                                      const float* __restrict__ dst,
                                                      float* __restrict__ out) {
    __shared__ float pbuf[4][EDGE_CAP];
    __shared__ int   cbuf[4][EDGE_CAP];
    int wav  = threadIdx.x >> 6;
    int lane = threadIdx.x & 63;
    int row  = blockIdx.x * 4 + wav;
    int n    = cnt[row];
    const int* cr = col + (size_t)row * EDGE_CAP;
    float si = src[row];

    float m = -3.0e38f;
    for (int e = lane; e < n; e += 64) {
        int j = cr[e];
        float x = si + dst[j];
        x = x > 0.0f ? x : 0.2f * x;
        cbuf[wav][e] = j;
        pbuf[wav][e] = x;
        m = fmaxf(m, x);
    }
    #pragma unroll
    for (int off = 32; off; off >>= 1) m = fmaxf(m, __shfl_xor(m, off));

    float ssum = 0.0f;
    for (int e = lane; e < n; e += 64) {
        float p = __expf(pbuf[wav][e] - m);
        pbuf[wav][e] = p;
        ssum += p;
    }
    #pragma unroll
    for (int off = 32; off; off >>= 1) ssum += __shfl_xor(ssum, off);
    float inv = 1.0f / ssum;

    float o = 0.0f;
    int e = 0;
    for (; e + 8 <= n; e += 8) {
        float v[8]; float p[8];
        #pragma unroll
        for (int u = 0; u < 8; ++u) {
            p[u] = pbuf[wav][e + u];
            v[u] = H[(size_t)cbuf[wav][e + u] * 64 + lane];
        }
        #pragma unroll
        for (int u = 0; u < 8; ++u) o += p[u] * v[u];
    }
    for (; e < n; ++e) o += pbuf[wav][e] * H[(size_t)cbuf[wav][e] * 64 + lane];

    // one class per lane; fused log_softmax across the wave
    float logit = o * inv;
    float mm = logit;
    #pragma unroll
    for (int off = 32; off; off >>= 1) mm = fmaxf(mm, __shfl_xor(mm, off));
    float se = __expf(logit - mm);
    #pragma unroll
    for (int off = 32; off; off >>= 1) se += __shfl_xor(se, off);
    out[(size_t)row * 64 + lane] = logit - mm - logf(se);
}

// ---------------------------------------------------------------------------
extern "C" void kernel_launch(void* const* d_in, const int* in_sizes, int n_in,
                              void* d_out, int out_size, void* d_ws, size_t ws_size,
                              hipStream_t stream) {
    const float* feat = (const float*)d_in[0];   // (8192, 256)
    const float* adj  = (const float*)d_in[1];   // (8192, 8192)
    const float* W0   = (const float*)d_in[2];   // (512, 128)
    const float* a0   = (const float*)d_in[3];   // (256,)
    const float* W1   = (const float*)d_in[4];   // (256, 64)
    const float* a1   = (const float*)d_in[5];   // (128,)
    float* out = (float*)d_out;                  // (8192, 64)

    // workspace layout (~23 MB total)
    char* w = (char*)d_ws;
    int* cnt = (int*)w;                w += (size_t)NROWS * sizeof(int);
    int* col = (int*)w;                w += (size_t)NROWS * EDGE_CAP * sizeof(int);
    float* Y1   = (float*)w;           w += (size_t)NROWS * 128 * sizeof(float);
    float* Z1   = (float*)w;           w += (size_t)NROWS * 128 * sizeof(float);
    float* H1   = (float*)w;           w += (size_t)NROWS * 128 * sizeof(float);
    float* src1 = (float*)w;           w += (size_t)NROWS * sizeof(float);
    float* dst1 = (float*)w;           w += (size_t)NROWS * sizeof(float);
    float* Y2   = (float*)w;           w += (size_t)NROWS * 64 * sizeof(float);
    float* Z2   = (float*)w;           w += (size_t)NROWS * 64 * sizeof(float);
    float* H2   = (float*)w;           w += (size_t)NROWS * 64 * sizeof(float);
    float* src2 = (float*)w;           w += (size_t)NROWS * sizeof(float);
    float* dst2 = (float*)w;           w += (size_t)NROWS * sizeof(float);

    // ---- fused: CSR build (blocks 256..2303) + layer-1 GEMM (blocks 0..255) ----
    fused_csr_gemm1<<<256 + NROWS / 4, 256, 0, stream>>>(adj, cnt, col, feat, W0, Y1, Z1);

    // ---- layer 1: spmm + scores, then aggregate + ELU + fused layer-2 GEMM ----
    spmm_add_scores<128><<<NROWS / 4, 256, 0, stream>>>(cnt, col, Y1, Z1, a0, H1, src1, dst1);
    attn_agg_gemm2<<<NROWS / 4, 256, 0, stream>>>(cnt, col, H1, src1, dst1, W1, Y2, Z2);

    // ---- layer 2 ----
    spmm_add_scores<64><<<NROWS / 4, 256, 0, stream>>>(cnt, col, Y2, Z2, a1, H2, src2, dst2);
    attn_agg_final<<<NROWS / 4, 256, 0, stream>>>(cnt, col, H2, src2, dst2, out);
}

// Round 6
// 430.469 us; speedup vs baseline: 1.2857x; 1.0047x over previous
//
#include <hip/hip_runtime.h>
#include <math.h>
#include <stdint.h>

// Problem constants (from reference): N=8192, F=256, HID=128, C=64
#define NROWS 8192
#define EDGE_CAP 128   // max row degree ~70 (Binomial(8192,0.005)); 128 is safe

using f4v = __attribute__((ext_vector_type(4))) float;

// bf16 helpers (RNE pack, shift unpack); values are finite here.
// PRECISION NOTE: attention scores are near winner-take-all (score std ~16/~56),
// so anything upstream of src/dst must stay fp32 (bf16 noise flips argmax ->
// O(100) output errors, measured R5). Only the FINAL H2 gather is flip-safe.
__device__ __forceinline__ uint16_t bfpack(float f) {
    uint32_t x = __float_as_uint(f);
    return (uint16_t)((x + 0x7FFFu + ((x >> 16) & 1u)) >> 16);
}
__device__ __forceinline__ float bfun(uint16_t u) {
    return __uint_as_float((uint32_t)u << 16);
}

// ---------------------------------------------------------------------------
// K1 (fused, heterogeneous): blocks [0,256)   : Y|Z = feat @ [W0_top || W0_bot]
//                            blocks [256,2304): dense adj -> fixed-stride CSR
// CSR scan uses non-temporal loads: adj is read-once, keep it out of L2.
// ---------------------------------------------------------------------------
__global__ __launch_bounds__(256) void fused_csr_gemm1(const float* __restrict__ adj,
                                                       int* __restrict__ cnt,
                                                       int* __restrict__ col,
                                                       const float* __restrict__ A,
                                                       const float* __restrict__ W,
                                                       float* __restrict__ Y,
                                                       float* __restrict__ Z) {
    __shared__ float As[16][64];     // 4 KB
    __shared__ float Bs[16][128];    // 8 KB
    int gb  = blockIdx.x;
    int tid = threadIdx.x;

    if (gb < 256) {
        // ---- GEMM role: BM=64, BN=128, K=256; 4x8 per thread ----
        int bm = gb & 127, bn = gb >> 7;          // bn=0 -> Y, bn=1 -> Z
        int tx = tid & 15, ty = tid >> 4;
        const float* Wb = W + (size_t)bn * 256 * 128;
        float acc[4][8] = {};
        for (int k0 = 0; k0 < 256; k0 += 16) {
            {   // A tile 64x16
                int r = tid >> 2, kk = (tid & 3) * 4;
                float4 v = *(const float4*)&A[(size_t)(bm * 64 + r) * 256 + k0 + kk];
                As[kk + 0][r] = v.x; As[kk + 1][r] = v.y;
                As[kk + 2][r] = v.z; As[kk + 3][r] = v.w;
            }
            {   // B tile 16x128
                int kk = tid >> 4, c = (tid & 15) * 8;
                *(float4*)&Bs[kk][c]     = *(const float4*)&Wb[(size_t)(k0 + kk) * 128 + c];
                *(float4*)&Bs[kk][c + 4] = *(const float4*)&Wb[(size_t)(k0 + kk) * 128 + c + 4];
            }
            __syncthreads();
            #pragma unroll
            for (int kk = 0; kk < 16; ++kk) {
                float a[4], b[8];
                #pragma unroll
                for (int i = 0; i < 4; ++i) a[i] = As[kk][ty * 4 + i];
                #pragma unroll
                for (int j = 0; j < 8; ++j) b[j] = Bs[kk][tx * 8 + j];
                #pragma unroll
                for (int i = 0; i < 4; ++i)
                    #pragma unroll
                    for (int j = 0; j < 8; ++j) acc[i][j] += a[i] * b[j];
            }
            __syncthreads();
        }
        float* O = bn ? Z : Y;
        #pragma unroll
        for (int i = 0; i < 4; ++i) {
            int r = bm * 64 + ty * 4 + i;
            float4 v0 = {acc[i][0], acc[i][1], acc[i][2], acc[i][3]};
            float4 v1 = {acc[i][4], acc[i][5], acc[i][6], acc[i][7]};
            *(float4*)&O[(size_t)r * 128 + tx * 8]     = v0;
            *(float4*)&O[(size_t)r * 128 + tx * 8 + 4] = v1;
        }
    } else {
        // ---- CSR role: wave per row, ballot compaction ----
        int row  = (gb - 256) * 4 + (tid >> 6);
        int lane = tid & 63;
        const f4v* arow = (const f4v*)(adj + (size_t)row * NROWS);
        int* crow = col + (size_t)row * EDGE_CAP;
        int count = 0;
        for (int it = 0; it < NROWS / 256; ++it) {   // 32 iters: 64 lanes x float4
            f4v v = __builtin_nontemporal_load(&arow[it * 64 + lane]);
            float vv[4] = {v.x, v.y, v.z, v.w};
            #pragma unroll
            for (int p = 0; p < 4; ++p) {
                bool nz = vv[p] > 0.0f;
                unsigned long long m = __ballot(nz);
                if (nz) {
                    int off = count + __popcll(m & ((1ull << lane) - 1ull));
                    if (off < EDGE_CAP) crow[off] = it * 256 + lane * 4 + p;
                }
                count += __popcll(m);   // wave-uniform
            }
        }
        if (lane == 0) cnt[row] = count < EDGE_CAP ? count : EDGE_CAP;
    }
}

// ---------------------------------------------------------------------------
// K2: H[i,:] = sum_{j in N(i)} Y[j,:] + Z[i,:]; src/dst attention dots fused.
// FOUT=128, all fp32. wave per row; edges staged in LDS; unrolled x8.
// ---------------------------------------------------------------------------
__global__ __launch_bounds__(256) void spmm_scores_128(const int* __restrict__ cnt,
                                                       const int* __restrict__ col,
                                                       const float* __restrict__ Y,
                                                       const float* __restrict__ Z,
                                                       const float* __restrict__ a,
                                                       float* __restrict__ H,
                                                       float* __restrict__ src,
                                                       float* __restrict__ dst) {
    __shared__ int sbuf[4][EDGE_CAP];
    int wav  = threadIdx.x >> 6;
    int lane = threadIdx.x & 63;
    int row  = blockIdx.x * 4 + wav;
    int n    = cnt[row];
    const int* cr = col + (size_t)row * EDGE_CAP;
    for (int e = lane; e < n; e += 64) sbuf[wav][e] = cr[e];
    // wave-local LDS: writes by this wave precede reads by this wave

    const float2* Y2 = (const float2*)Y;
    float2 s = {0.0f, 0.0f};
    int e = 0;
    for (; e + 8 <= n; e += 8) {
        float2 v[8];
        #pragma unroll
        for (int u = 0; u < 8; ++u) {
            int j = sbuf[wav][e + u];
            v[u] = Y2[(size_t)j * 64 + lane];
        }
        #pragma unroll
        for (int u = 0; u < 8; ++u) { s.x += v[u].x; s.y += v[u].y; }
    }
    for (; e < n; ++e) {
        int j = sbuf[wav][e];
        float2 v = Y2[(size_t)j * 64 + lane];
        s.x += v.x; s.y += v.y;
    }
    float2 z = ((const float2*)Z)[(size_t)row * 64 + lane];
    float hx = s.x + z.x, hy = s.y + z.y;
    float2 hv = {hx, hy};
    ((float2*)H)[(size_t)row * 64 + lane] = hv;
    float s1 = hx * a[lane * 2] + hy * a[lane * 2 + 1];
    float s2 = hx * a[128 + lane * 2] + hy * a[128 + lane * 2 + 1];
    #pragma unroll
    for (int off = 32; off; off >>= 1) {
        s1 += __shfl_xor(s1, off);
        s2 += __shfl_xor(s2, off);
    }
    if (lane == 0) { src[row] = s1; dst[row] = s2; }
}

// ---------------------------------------------------------------------------
// K3: layer-1 softmax-aggregate + ELU + fused layer-2 GEMM (lane = out col).
// X1 lives only in LDS; all fp32 (feeds layer-2 scores -> flip-sensitive).
// ---------------------------------------------------------------------------
__global__ __launch_bounds__(256) void attn_agg_gemm2(const int* __restrict__ cnt,
                                                      const int* __restrict__ col,
                                                      const float* __restrict__ H,
                                                      const float* __restrict__ src,
                                                      const float* __restrict__ dst,
                                                      const float* __restrict__ W1,
                                                      float* __restrict__ Y2,
                                                      float* __restrict__ Z2) {
    __shared__ float pbuf[4][EDGE_CAP];
    __shared__ int   cbuf[4][EDGE_CAP];
    __shared__ float xrow[4][128];
    int wav  = threadIdx.x >> 6;
    int lane = threadIdx.x & 63;
    int row  = blockIdx.x * 4 + wav;
    int n    = cnt[row];
    const int* cr = col + (size_t)row * EDGE_CAP;
    float si = src[row];

    // pass 1: e = leaky_relu(src_i + dst_j), row max (n <= 128 -> <= 2 iters)
    float m = -3.0e38f;
    for (int e = lane; e < n; e += 64) {
        int j = cr[e];
        float x = si + dst[j];
        x = x > 0.0f ? x : 0.2f * x;
        cbuf[wav][e] = j;
        pbuf[wav][e] = x;
        m = fmaxf(m, x);
    }
    #pragma unroll
    for (int off = 32; off; off >>= 1) m = fmaxf(m, __shfl_xor(m, off));

    // pass 2: exp, row sum  (non-edges contribute exp(-9e15 - m) == 0 exactly)
    float ssum = 0.0f;
    for (int e = lane; e < n; e += 64) {
        float p = __expf(pbuf[wav][e] - m);
        pbuf[wav][e] = p;
        ssum += p;
    }
    #pragma unroll
    for (int off = 32; off; off >>= 1) ssum += __shfl_xor(ssum, off);
    float inv = 1.0f / ssum;

    // pass 3: hp[i,c] = (1/sum) * sum_e p_e * H[j_e, c]; lane = column pair
    const float2* H2 = (const float2*)H;
    float2 o = {0.0f, 0.0f};
    int e = 0;
    for (; e + 8 <= n; e += 8) {
        float2 v[8]; float p[8];
        #pragma unroll
        for (int u = 0; u < 8; ++u) {
            int j = cbuf[wav][e + u];
            p[u] = pbuf[wav][e + u];
            v[u] = H2[(size_t)j * 64 + lane];
        }
        #pragma unroll
        for (int u = 0; u < 8; ++u) { o.x += p[u] * v[u].x; o.y += p[u] * v[u].y; }
    }
    for (; e < n; ++e) {
        int j = cbuf[wav][e];
        float p = pbuf[wav][e];
        float2 v = H2[(size_t)j * 64 + lane];
        o.x += p * v.x; o.y += p * v.y;
    }
    float vx = o.x * inv, vy = o.y * inv;
    vx = vx > 0.0f ? vx : (__expf(vx) - 1.0f);   // ELU, alpha=1
    vy = vy > 0.0f ? vy : (__expf(vy) - 1.0f);

    // stage X1 row in LDS (wave-local; lane holds cols 2*lane, 2*lane+1)
    float2 hv = {vx, vy};
    ((float2*)&xrow[wav][0])[lane] = hv;

    // fused layer-2 GEMV: lane = output column c
    float y = 0.0f, z = 0.0f;
    #pragma unroll 8
    for (int k = 0; k < 128; ++k) {
        float xk = xrow[wav][k];                       // LDS broadcast (free)
        y += xk * W1[(size_t)k * 64 + lane];           // W1 top half (rows 0..127)
        z += xk * W1[(size_t)(128 + k) * 64 + lane];   // W1 bottom half
    }
    Y2[(size_t)row * 64 + lane] = y;
    Z2[(size_t)row * 64 + lane] = z;
}

// ---------------------------------------------------------------------------
// K4: layer-2 spmm + scores (all fp32 in) ; H2 stored ONLY as bf16 — it is
// consumed solely by the final weighted average (no flip risk downstream).
// ---------------------------------------------------------------------------
__global__ __launch_bounds__(256) void spmm_scores_64(const int* __restrict__ cnt,
                                                      const int* __restrict__ col,
                                                      const float* __restrict__ Y,
                                                      const float* __restrict__ Z,
                                                      const float* __restrict__ a,
                                                      uint16_t* __restrict__ Hb,
                                                      float* __restrict__ src,
                                                      float* __restrict__ dst) {
    __shared__ int sbuf[4][EDGE_CAP];
    int wav  = threadIdx.x >> 6;
    int lane = threadIdx.x & 63;
    int row  = blockIdx.x * 4 + wav;
    int n    = cnt[row];
    const int* cr = col + (size_t)row * EDGE_CAP;
    for (int e = lane; e < n; e += 64) sbuf[wav][e] = cr[e];

    float s = 0.0f;
    int e = 0;
    for (; e + 8 <= n; e += 8) {
        float v[8];
        #pragma unroll
        for (int u = 0; u < 8; ++u) v[u] = Y[(size_t)sbuf[wav][e + u] * 64 + lane];
        #pragma unroll
        for (int u = 0; u < 8; ++u) s += v[u];
    }
    for (; e < n; ++e) s += Y[(size_t)sbuf[wav][e] * 64 + lane];
    float h = s + Z[(size_t)row * 64 + lane];
    Hb[(size_t)row * 64 + lane] = bfpack(h);     // bf16 copy for final gather
    float s1 = h * a[lane];                      // scores from fp32 h
    float s2 = h * a[64 + lane];
    #pragma unroll
    for (int off = 32; off; off >>= 1) {
        s1 += __shfl_xor(s1, off);
        s2 += __shfl_xor(s2, off);
    }
    if (lane == 0) { src[row] = s1; dst[row] = s2; }
}

// ---------------------------------------------------------------------------
// K5: layer-2 softmax-aggregate + fused log_softmax (64 classes, lane=class)
// H2 gathered as bf16 (halved gather bytes; output-only perturbation ~0.1).
// ---------------------------------------------------------------------------
__global__ __launch_bounds__(256) void attn_agg_final(const int* __restrict__ cnt,
                                                      const int* __restrict__ col,
                                                      const uint16_t* __restrict__ Hb,
                                                      const float* __restrict__ src,
                                                      const float* __restrict__ dst,
                                                      float* __restrict__ out) {
    __shared__ float pbuf[4][EDGE_CAP];
    __shared__ int   cbuf[4][EDGE_CAP];
    int wav  = threadIdx.x >> 6;
    int lane = threadIdx.x & 63;
    int row  = blockIdx.x * 4 + wav;
    int n    = cnt[row];
    const int* cr = col + (size_t)row * EDGE_CAP;
    float si = src[row];

    float m = -3.0e38f;
    for (int e = lane; e < n; e += 64) {
        int j = cr[e];
        float x = si + dst[j];
        x = x > 0.0f ? x : 0.2f * x;
        cbuf[wav][e] = j;
        pbuf[wav][e] = x;
        m = fmaxf(m, x);
    }
    #pragma unroll
    for (int off = 32; off; off >>= 1) m = fmaxf(m, __shfl_xor(m, off));

    float ssum = 0.0f;
    for (int e = lane; e < n; e += 64) {
        float p = __expf(pbuf[wav][e] - m);
        pbuf[wav][e] = p;
        ssum += p;
    }
    #pragma unroll
    for (int off = 32; off; off >>= 1) ssum += __shfl_xor(ssum, off);
    float inv = 1.0f / ssum;

    float o = 0.0f;
    int e = 0;
    for (; e + 8 <= n; e += 8) {
        uint16_t v[8]; float p[8];
        #pragma unroll
        for (int u = 0; u < 8; ++u) {
            p[u] = pbuf[wav][e + u];
            v[u] = Hb[(size_t)cbuf[wav][e + u] * 64 + lane];
        }
        #pragma unroll
        for (int u = 0; u < 8; ++u) o += p[u] * bfun(v[u]);
    }
    for (; e < n; ++e) o += pbuf[wav][e] * bfun(Hb[(size_t)cbuf[wav][e] * 64 + lane]);

    // one class per lane; fused log_softmax across the wave
    float logit = o * inv;
    float mm = logit;
    #pragma unroll
    for (int off = 32; off; off >>= 1) mm = fmaxf(mm, __shfl_xor(mm, off));
    float se = __expf(logit - mm);
    #pragma unroll
    for (int off = 32; off; off >>= 1) se += __shfl_xor(se, off);
    out[(size_t)row * 64 + lane] = logit - mm - logf(se);
}

// ---------------------------------------------------------------------------
extern "C" void kernel_launch(void* const* d_in, const int* in_sizes, int n_in,
                              void* d_out, int out_size, void* d_ws, size_t ws_size,
                              hipStream_t stream) {
    const float* feat = (const float*)d_in[0];   // (8192, 256)
    const float* adj  = (const float*)d_in[1];   // (8192, 8192)
    const float* W0   = (const float*)d_in[2];   // (512, 128)
    const float* a0   = (const float*)d_in[3];   // (256,)
    const float* W1   = (const float*)d_in[4];   // (256, 64)
    const float* a1   = (const float*)d_in[5];   // (128,)
    float* out = (float*)d_out;                  // (8192, 64)

    // workspace layout (~22 MB total)
    char* w = (char*)d_ws;
    int* cnt      = (int*)w;        w += (size_t)NROWS * sizeof(int);
    int* col      = (int*)w;        w += (size_t)NROWS * EDGE_CAP * sizeof(int);
    float* Y1   = (float*)w;        w += (size_t)NROWS * 128 * sizeof(float);
    float* Z1   = (float*)w;        w += (size_t)NROWS * 128 * sizeof(float);
    float* H1   = (float*)w;        w += (size_t)NROWS * 128 * sizeof(float);
    float* Y2   = (float*)w;        w += (size_t)NROWS * 64 * sizeof(float);
    float* Z2   = (float*)w;        w += (size_t)NROWS * 64 * sizeof(float);
    uint16_t* H2b = (uint16_t*)w;   w += (size_t)NROWS * 64 * sizeof(uint16_t);
    float* src1 = (float*)w;        w += (size_t)NROWS * sizeof(float);
    float* dst1 = (float*)w;        w += (size_t)NROWS * sizeof(float);
    float* src2 = (float*)w;        w += (size_t)NROWS * sizeof(float);
    float* dst2 = (float*)w;        w += (size_t)NROWS * sizeof(float);

    // ---- fused: CSR build (blocks 256..2303) + layer-1 GEMM (blocks 0..255) ----
    fused_csr_gemm1<<<256 + NROWS / 4, 256, 0, stream>>>(adj, cnt, col, feat, W0, Y1, Z1);

    // ---- layer 1: spmm + scores, then aggregate + ELU + fused layer-2 GEMM ----
    spmm_scores_128<<<NROWS / 4, 256, 0, stream>>>(cnt, col, Y1, Z1, a0, H1, src1, dst1);
    attn_agg_gemm2<<<NROWS / 4, 256, 0, stream>>>(cnt, col, H1, src1, dst1, W1, Y2, Z2);

    // ---- layer 2 ----
    spmm_scores_64<<<NROWS / 4, 256, 0, stream>>>(cnt, col, Y2, Z2, a1, H2b, src2, dst2);
    attn_agg_final<<<NROWS / 4, 256, 0, stream>>>(cnt, col, H2b, src2, dst2, out);
}